// Round 14
// baseline (12.987 us; speedup 1.0000x reference)
//
#include <hip/hip_runtime.h>

typedef unsigned int u32;
typedef unsigned long long u64;
typedef float f4 __attribute__((ext_vector_type(4)));   // native vec for nt-store

// AdderNet conv+ReLU: out[n,o,h,w] = relu(b[o] - sum_{c,kh,kw} |x - w|)
// x:[8,64,128,128] f32, w:[64,64,3,3], b:[64], out:[8,64,128,128] f32.
//
// Triangle-inequality screen over a SUBSET of terms (valid for all inputs):
//   sum_{all} |x_patch - w[o]| >= S'(n,h,w) - Wsum'[o]
// subset = channels 0..11, center input row (kh=1), in-bounds cols:
//   S' = sum_{dc,-1..1, in-bounds} A12(n,h,w+dc),  A12 = sum_{c<12} |x|
//   Wsum'[o] = sum_{c<12} sum_{kw} |w[o,c,1,kw]|
// If S' >= thr = max_o(Wsum'[o]+b[o]) + 1.0 slack, all 64 outputs at that
// pixel are exactly 0; failing cols get an exact fp32 recompute (correct for
// arbitrary inputs). Unit-scale margins: 4.3 sigma edge / 6.2 interior.
//
// r14 lever: STORE IGNITION DELAY. All r8-r13 variants gate each block's
// 64KB store burst behind loads+LDS+barrier (~1.5-2us chip-wide write-stream
// delay + per-block gaps). Now ONE WAVE = one row, NO LDS, NO barriers:
//   issue 12 x-loads -> issue 36 w-loads -> issue 32 nt-stores (zero deps,
//   ~50cy after wave start) -> consume loads (compiler emits vmcnt(32):
//   loads precede stores in issue order, so waiting for loads NEVER drains
//   the store burst) -> in-register screen via shuffles -> ballot -> done.
// Fix-up path (never taken) does its own vmcnt(0) before overwriting.

#define Hh 128
#define Ww 128
#define C_IN 64
#define O_OUT 64
#define NB 8
#define PIX (Hh * Ww)
#define CS 12                    // screened channels

__global__ __launch_bounds__(64)
void adder_wave_row(const float* __restrict__ x, const float* __restrict__ w,
                    const float* __restrict__ b, float* __restrict__ out) {
    const int bid  = blockIdx.x;     // 0..1023
    const int n    = bid >> 7;       // image
    const int h    = bid & 127;      // row
    const int lane = threadIdx.x;    // 0..63

    // ---- 1) x loads: 12 channel-rows; lane -> cols {2*lane, 2*lane+1} ----
    // each instr: 64 lanes x 8B = one full 512B channel-row, contiguous.
    const float2* xr = (const float2*)(x + (size_t)n * C_IN * PIX
                                         + (size_t)h * Ww) + lane;
    float2 xv[CS];
    #pragma unroll
    for (int c = 0; c < CS; ++c) xv[c] = xr[(size_t)c * (PIX / 2)];

    // ---- 2) w loads ISSUED here, consumed after stores (lane -> o = lane) ----
    const float* wo = w + (size_t)lane * 576 + 3;    // [o][c][kh=1][kw0]
    float wv[CS][3];
    #pragma unroll
    for (int c = 0; c < CS; ++c) {
        wv[c][0] = wo[c * 9 + 0];
        wv[c][1] = wo[c * 9 + 1];
        wv[c][2] = wo[c * 9 + 2];
    }
    const float bo = b[lane];

    // ---- 3) zero-store burst: 64 o-planes x row h, nt, issues immediately ----
    // instr j: lanes 0-31 -> o=2j (512B contiguous), lanes 32-63 -> o=2j+1.
    f4* outr = (f4*)(out + (size_t)n * O_OUT * PIX + (size_t)h * Ww);
    const f4 z = (f4){0.f, 0.f, 0.f, 0.f};
    const int oh = lane >> 5, fc = lane & 31;
    #pragma unroll
    for (int j = 0; j < 32; ++j) {
        const int o = j * 2 + oh;
        __builtin_nontemporal_store(z, &outr[(size_t)o * (PIX / 4) + fc]);
    }

    // ---- 4) thr = max_o( sum_{c<12}|w[o,c,1,:]| + b[o] ) + slack ----
    float s = 0.f;
    #pragma unroll
    for (int c = 0; c < CS; ++c)
        s += fabsf(wv[c][0]) + fabsf(wv[c][1]) + fabsf(wv[c][2]);
    float v = s + bo;
    #pragma unroll
    for (int d = 1; d < 64; d <<= 1) v = fmaxf(v, __shfl_xor(v, d));
    const float thr = v + 1.0f;   // >> fp32 summation-order error, << margin

    // ---- 5) in-register screen: A12 pair + neighbor taps via shuffles ----
    float ae = 0.f, ao = 0.f;     // A12 at cols 2*lane, 2*lane+1
    #pragma unroll
    for (int c = 0; c < CS; ++c) { ae += fabsf(xv[c].x); ao += fabsf(xv[c].y); }
    const float pao = __shfl_up(ao, 1);     // lane-1's odd-col A12
    const float nae = __shfl_down(ae, 1);   // lane+1's even-col A12
    const float S0 = ae + ao + (lane > 0  ? pao : 0.f);   // box at col 2*lane
    const float S1 = ae + ao + (lane < 63 ? nae : 0.f);   // box at col 2*lane+1
    const u64 b0 = __ballot(!(S0 >= thr));
    const u64 b1 = __ballot(!(S1 >= thr));
    // common path ends here: no barrier, stores still in flight.

    // ---- 6) exact fp32 fix-up (wave-local; normally never taken) ----
    if (b0 | b1) {
        asm volatile("s_waitcnt vmcnt(0)" ::: "memory");  // own zeros ordered
        const float* xs  = x + (size_t)n * C_IN * PIX;
        const int    o   = lane;                          // 64 lanes = 64 o
        const float* woF = w + (size_t)o * 576;
        #pragma unroll 1
        for (int half = 0; half < 2; ++half) {
            u64 m = half ? b1 : b0;
            while (m) {
                const int bit = __ffsll((unsigned long long)m) - 1;
                m &= m - 1;
                const int col = bit * 2 + half;
                float sum = 0.f;
                for (int c = 0; c < C_IN; ++c) {
                    const float* xc = xs + (size_t)c * PIX;
                    const float* wc = woF + c * 9;
                    #pragma unroll
                    for (int kh = 0; kh < 3; ++kh) {
                        const int gh = h + kh - 1;
                        #pragma unroll
                        for (int kw = 0; kw < 3; ++kw) {
                            const int gw = col + kw - 1;
                            const float xval = ((unsigned)gh < (unsigned)Hh &&
                                                (unsigned)gw < (unsigned)Ww)
                                               ? xc[gh * Ww + gw] : 0.f;
                            sum += fabsf(xval - wc[kh * 3 + kw]);
                        }
                    }
                }
                out[(size_t)(n * O_OUT + o) * PIX + h * Ww + col] =
                    fmaxf(bo - sum, 0.f);
            }
        }
    }
}

extern "C" void kernel_launch(void* const* d_in, const int* in_sizes, int n_in,
                              void* d_out, int out_size, void* d_ws, size_t ws_size,
                              hipStream_t stream) {
    const float* x = (const float*)d_in[0];
    const float* w = (const float*)d_in[1];
    const float* b = (const float*)d_in[2];
    float* out = (float*)d_out;

    adder_wave_row<<<NB * Hh, 64, 0, stream>>>(x, w, b, out);
}